// Round 18
// baseline (348.372 us; speedup 1.0000x reference)
//
#include <hip/hip_runtime.h>
#include <hip/hip_bf16.h>
#include <stdint.h>

// ---------------- problem dims ----------------
#define BTOT   65536
#define DIN    784
#define NH1    256
#define NH2    64
#define NEXP   10
#define BM     256
#define NKS1   25      // K1 = 800 (784 + bias row @784 + zeros), 25 steps of 32

// ---------------- LDS layout (bytes) ----------------
// 4-slot staging ring, 32 KB each (x 16K | w 16K). h (128 KB, FULL) overlays
// the whole ring — used only after the K-loop fully drains.
#define SLOT(s)   (lds + (s) * 32768)
#define EXPL_OFF  131072                   // [256 m][10 e] f32 = 10240
#define B2S_OFF   141312                   // [10][64] f32 = 2560
#define W3S_OFF   143872                   // [10][64] f32 = 2560
#define B3S_OFF   146432                   // 64
#define BG2S_OFF  146496                   // 64
#define LDS_TOTAL 146560

typedef short s16x8  __attribute__((ext_vector_type(8)));
typedef float f32x4  __attribute__((ext_vector_type(4)));
typedef float f32x16 __attribute__((ext_vector_type(16)));

__device__ __forceinline__ short bf16b(float v) {
    __bf16 b = (__bf16)v;
    return __builtin_bit_cast(short, b);
}

__device__ __forceinline__ void g2l16(const void* g, void* l) {
    __builtin_amdgcn_global_load_lds(
        (const __attribute__((address_space(1))) unsigned char*)g,
        (__attribute__((address_space(3))) unsigned char*)l, 16, 0, 0);
}

// ---------------- prep: fragment-order weights (bf16, b1 folded) ------------
// w1t [e11][ks25][nb8][kh2][lane64][8]: n=nb*32+(lane&31),
// k=ks*32+kh*16+(lane>>5)*8+j; k==784 -> bias; e==10 -> gate Wg1/bg1.
__global__ void prep_w1(const float* __restrict__ W1, const float* __restrict__ b1,
                        const float* __restrict__ Wg1, const float* __restrict__ bg1,
                        __bf16* __restrict__ dst) {
    int t = blockIdx.x * 256 + threadIdx.x;          // < 281600
    int lane = t & 63;
    int kh = (t >> 6) & 1;
    int nb = (t >> 7) & 7;
    int r  = t >> 10;
    int ks = r % 25, e = r / 25;
    int n  = nb * 32 + (lane & 31);
    int k0 = ks * 32 + kh * 16 + (lane >> 5) * 8;
    const float* src  = (e < NEXP) ? (W1 + (size_t)e * DIN * NH1) : Wg1;
    const float* bias = (e < NEXP) ? (b1 + e * NH1) : bg1;
    s16x8 o;
    #pragma unroll
    for (int j = 0; j < 8; ++j) {
        int k = k0 + j;
        float v = (k < DIN) ? src[(size_t)k * NH1 + n]
                            : ((k == DIN) ? bias[n] : 0.f);
        o[j] = bf16b(v);
    }
    *(s16x8*)((short*)dst + (size_t)t * 8) = o;
}

// w2t [e10][jb2][ks8][kh2][lane64][8]: n=jb*32+(lane&31), K2=256.
__global__ void prep_w2(const float* __restrict__ W2, __bf16* __restrict__ dst) {
    int t = blockIdx.x * 256 + threadIdx.x;          // < 20480
    int lane = t & 63;
    int kh = (t >> 6) & 1;
    int ks = (t >> 7) & 7;
    int jb = (t >> 10) & 1;
    int e  = t >> 11;
    int n  = jb * 32 + (lane & 31);
    int k0 = ks * 32 + kh * 16 + (lane >> 5) * 8;
    s16x8 o;
    #pragma unroll
    for (int j = 0; j < 8; ++j)
        o[j] = bf16b(W2[((size_t)e * NH1 + k0 + j) * NH2 + n]);
    *(s16x8*)((short*)dst + (size_t)t * 8) = o;
}

// wg2t [ks8][kh2][lane64][8]: col = lane&31 (valid <10), K2=256.
__global__ void prep_wg2(const float* __restrict__ Wg2, __bf16* __restrict__ dst) {
    int t = blockIdx.x * 256 + threadIdx.x;
    if (t >= 1024) return;
    int lane = t & 63;
    int kh = (t >> 6) & 1;
    int ks = t >> 7;
    int n  = lane & 31;
    int k0 = ks * 32 + kh * 16 + (lane >> 5) * 8;
    s16x8 o;
    #pragma unroll
    for (int j = 0; j < 8; ++j)
        o[j] = bf16b((n < NEXP) ? Wg2[(size_t)(k0 + j) * NEXP + n] : 0.f);
    *(s16x8*)((short*)dst + (size_t)t * 8) = o;
}

// ---- staging + body macros ----
#define STAGE(S, E, KS) {                                                     \
        const char* xs_ = xtc + ((size_t)(KS) << 14) + tid * 16;              \
        char* xd_ = SLOT(S) + tid * 16;                                       \
        g2l16(xs_, xd_); g2l16(xs_ + 8192, xd_ + 8192);                       \
        const char* ws_ = w1c + (((size_t)(E) * 25 + (KS)) << 14) + tid * 16; \
        char* wd_ = SLOT(S) + 16384 + tid * 16;                               \
        g2l16(ws_, wd_); g2l16(ws_ + 8192, wd_ + 8192); }

// w-only stage (e=0 path)
#define WSTAGE1(S, KS) {                                                      \
        const char* ws_ = w1c + ((size_t)(KS) << 14) + tid * 16;              \
        char* wd_ = SLOT(S) + 16384 + tid * 16;                               \
        g2l16(ws_, wd_); g2l16(ws_ + 8192, wd_ + 8192); }

// e=0: load 16 fp32 of x (row xrow, k-half xkh) into xf; ks=24 upper half is
// the bias-1 + zero pad (k=784..799).
#define XLOAD(KS) { if ((KS) < 24 || xkh == 0) {                              \
            _Pragma("unroll") for (int i4 = 0; i4 < 4; ++i4)                  \
                *(float4*)(xf + 4 * i4) =                                     \
                    *(const float4*)(xrp + (KS) * 32 + 4 * i4);               \
        } else { _Pragma("unroll") for (int i4 = 0; i4 < 16; ++i4)            \
                     xf[i4] = 0.f;                                            \
                 xf[0] = 1.f; } }

// e=0: convert + write to LDS slot x-region AND write-through fragment-order
// xt (global; only this block reads it back).
#define XWRITE(B, KS) { s16x8 l8, h8;                                         \
        _Pragma("unroll") for (int j = 0; j < 8; ++j) {                       \
            l8[j] = bf16b(xf[j]); h8[j] = bf16b(xf[8 + j]); }                 \
        *(s16x8*)(SLOT(B) + xoff)       = l8;                                 \
        *(s16x8*)(SLOT(B) + xoff + 512) = h8;                                 \
        char* xg_ = xtw + ((size_t)(KS) << 14) + xoff;                        \
        *(s16x8*)xg_ = l8; *(s16x8*)(xg_ + 512) = h8; }

#define COMPUTE(S) {                                                          \
        const char* ab = SLOT(S) + mw * 4096 + lane * 16;                     \
        const char* wb = SLOT(S) + 16384 + nw * 8192 + lane * 16;             \
        s16x8 xv[2][2], wv[4][2];                                             \
        _Pragma("unroll") for (int mt = 0; mt < 2; ++mt)                      \
            _Pragma("unroll") for (int kh = 0; kh < 2; ++kh)                  \
                xv[mt][kh] = *(const s16x8*)(ab + (mt * 2 + kh) * 1024);      \
        _Pragma("unroll") for (int nt = 0; nt < 4; ++nt)                      \
            _Pragma("unroll") for (int kh = 0; kh < 2; ++kh)                  \
                wv[nt][kh] = *(const s16x8*)(wb + (nt * 2 + kh) * 1024);      \
        _Pragma("unroll") for (int kh = 0; kh < 2; ++kh)                      \
            _Pragma("unroll") for (int nt = 0; nt < 4; ++nt)                  \
                _Pragma("unroll") for (int mt = 0; mt < 2; ++mt)              \
                    acc[nt][mt] = __builtin_amdgcn_mfma_f32_32x32x16_bf16(    \
                        wv[nt][kh], xv[mt][kh], acc[nt][mt], 0, 0, 0); }

// counted-vmcnt sync wall (wait-own-ops THEN barrier)
#define RING_SYNC(VN) {                                                       \
        asm volatile("s_waitcnt vmcnt(" #VN ")" ::: "memory");                \
        __builtin_amdgcn_s_barrier();                                         \
        asm volatile("" ::: "memory"); }

// ring body (steady state): sync -> ds_reads -> stage issue (hides under
// MFMA) -> pinned setprio MFMA cluster. WAR-safe: slot (S+3)&3's readers
// finished before this body's barrier.
#define BODY(S, KS) {                                                         \
        RING_SYNC(8)                                                          \
        const char* ab = SLOT(S) + mw * 4096 + lane * 16;                     \
        const char* wb = SLOT(S) + 16384 + nw * 8192 + lane * 16;             \
        s16x8 xv[2][2], wv[4][2];                                             \
        _Pragma("unroll") for (int mt = 0; mt < 2; ++mt)                      \
            _Pragma("unroll") for (int kh = 0; kh < 2; ++kh)                  \
                xv[mt][kh] = *(const s16x8*)(ab + (mt * 2 + kh) * 1024);      \
        _Pragma("unroll") for (int nt = 0; nt < 4; ++nt)                      \
            _Pragma("unroll") for (int kh = 0; kh < 2; ++kh)                  \
                wv[nt][kh] = *(const s16x8*)(wb + (nt * 2 + kh) * 1024);      \
        STAGE(((S) + 3) & 3, e, (KS) + 3)                                     \
        __builtin_amdgcn_sched_barrier(0);                                    \
        __builtin_amdgcn_s_setprio(1);                                        \
        _Pragma("unroll") for (int kh = 0; kh < 2; ++kh)                      \
            _Pragma("unroll") for (int nt = 0; nt < 4; ++nt)                  \
                _Pragma("unroll") for (int mt = 0; mt < 2; ++mt)              \
                    acc[nt][mt] = __builtin_amdgcn_mfma_f32_32x32x16_bf16(    \
                        wv[nt][kh], xv[mt][kh], acc[nt][mt], 0, 0, 0);        \
        __builtin_amdgcn_s_setprio(0); }

// e=0 body: counted sync (no store/g2l full drain), compute, issue next
// iter's loads/stage/convert. Per-iter issue order: x-loads(2), W-g2l(2),
// xt-stores(2) -> vmcnt(2) at next sync drains loads+g2l (W ready), leaves
// the 2 stores in flight. ds_write visibility via lgkmcnt(0)+barrier.
#define E0BODY(CUR, KS) {                                                     \
        asm volatile("s_waitcnt vmcnt(2)" ::: "memory");                      \
        __builtin_amdgcn_s_barrier();                                         \
        asm volatile("" ::: "memory");                                        \
        COMPUTE(CUR)                                                          \
        if ((KS) < 24) {                                                      \
            XLOAD((KS) + 1)                                                   \
            WSTAGE1((CUR) ^ 1, (KS) + 1)                                      \
            XWRITE((CUR) ^ 1, (KS) + 1)                                       \
        }                                                                     \
        asm volatile("s_waitcnt lgkmcnt(0)" ::: "memory"); }

// ---------------- fused MoE kernel ----------------
// 256 blocks x 512 thr (8 waves, 1 block/CU, 2 waves/SIMD). Per expert:
// 256x256 layer-1 GEMM, K-step 32. e=0: counted-vmcnt 2-slot loop converting
// x fp32->bf16 into the slot AND writing fragment-order xt (no per-step
// store drain). e>=1 + gate: 4-slot depth-3 counted ring with stage-early +
// setprio MFMA cluster. h written FULL (ring overlay) -> no spill.
// mfma(W, x): D[n][m], m = lane&31, n = (r&3)+8*(r>>2)+4*(lane>>5).
__global__ void __launch_bounds__(512)
__attribute__((amdgpu_waves_per_eu(2, 2)))
moe_fused(const float* __restrict__ x, __bf16* __restrict__ xt,
          const float* __restrict__ b2g, const float* __restrict__ W3,
          const float* __restrict__ b3, const float* __restrict__ bg2,
          const __bf16* __restrict__ w1t, const __bf16* __restrict__ w2t,
          const __bf16* __restrict__ wg2t, float* __restrict__ out)
{
    extern __shared__ char lds[];
    char*  hb   = lds;                     // FULL h: [mtile8][ks2_8][kh2][1024B]
    float* expl = (float*)(lds + EXPL_OFF);
    float* b2s  = (float*)(lds + B2S_OFF);
    float* w3s  = (float*)(lds + W3S_OFF);
    float* b3s  = (float*)(lds + B3S_OFF);
    float* bg2s = (float*)(lds + BG2S_OFF);

    const int tid  = threadIdx.x;
    const int lane = tid & 63;
    const int wave = tid >> 6;             // 0..7
    const int rl   = lane & 31;
    const int hi   = lane >> 5;
    const int mw   = wave >> 1;            // 0..3 (64-row slice)
    const int nw   = wave & 1;             // 0..1 (128-col half)
    const int row0 = blockIdx.x * BM;
    const char* w1c = (const char*)w1t;
    const char* w2c = (const char*)w2t;
    const char* wgc = (const char*)wg2t;
    const char* xtc = (const char*)xt + ((size_t)blockIdx.x * 25 << 14);
    char*       xtw = (char*)xt + ((size_t)blockIdx.x * 25 << 14);

    // e=0 x-staging coords: thread -> (row, k-half)
    const int xrow = tid >> 1, xkh = tid & 1;
    const float* xrp = x + (size_t)(row0 + xrow) * DIN + xkh * 16;
    const int xoff = ((xrow >> 5) * 2 + xkh) * 1024 + (xrow & 31) * 16;
    float xf[16];

    for (int i = tid; i < NEXP * NH2; i += 512) { b2s[i] = b2g[i]; w3s[i] = W3[i]; }
    if (tid < NEXP) { b3s[tid] = b3[tid]; bg2s[tid] = bg2[tid]; }
    __syncthreads();                       // drains vmcnt -> known 0

    f32x16 acc[4][2];                      // [nt][mt] (layer-1)

    #pragma unroll 1
    for (int e = 0; e <= NEXP; ++e) {
        #pragma unroll
        for (int nt = 0; nt < 4; ++nt)
            #pragma unroll
            for (int mt = 0; mt < 2; ++mt)
                #pragma unroll
                for (int q = 0; q < 16; ++q) acc[nt][mt][q] = 0.f;

        if (e == 0) {
            // ---- e=0: counted 2-slot loop, x fp32->bf16 + xt write ----
            XLOAD(0)
            WSTAGE1(0, 0)
            XWRITE(0, 0)
            asm volatile("s_waitcnt lgkmcnt(0)" ::: "memory");
            #pragma unroll 1
            for (int T = 0; T < 12; ++T) {
                E0BODY(0, 2 * T)
                E0BODY(1, 2 * T + 1)
            }
            // final ks=24 (slot 0): W(24) staged at ks=23; only 2 stores newer
            asm volatile("s_waitcnt vmcnt(2)" ::: "memory");
            __builtin_amdgcn_s_barrier();
            asm volatile("" ::: "memory");
            COMPUTE(0)
            __syncthreads();               // drains xt stores; h may overlay
        } else {
            // ---- e>=1 / gate: 4-slot depth-3 counted ring ----
            STAGE(0, e, 0)
            STAGE(1, e, 1)
            STAGE(2, e, 2)
            #pragma unroll 1
            for (int T = 0; T < 5; ++T) {
                const int k4 = 4 * T;
                BODY(0, k4)
                BODY(1, k4 + 1)
                BODY(2, k4 + 2)
                BODY(3, k4 + 3)
            }
            BODY(0, 20)                    // stages ks=23 -> slot 3
            BODY(1, 21)                    // stages ks=24 -> slot 0
            RING_SYNC(8)  COMPUTE(2)       // ks=22 (no stage)
            RING_SYNC(4)  COMPUTE(3)       // ks=23
            RING_SYNC(0)  COMPUTE(0)       // ks=24
            __syncthreads();               // all ring reads done; h may overlay
        }

        // ---- h-write (FULL): value (nt,mt,q,r2) ->
        //      h[m=(mw*2+mt)*32+rl][n=nw*128+nt*32+(r2+8q+4hi)]
        #pragma unroll
        for (int mt = 0; mt < 2; ++mt)
            #pragma unroll
            for (int nt = 0; nt < 4; ++nt)
                #pragma unroll
                for (int q = 0; q < 4; ++q) {
                    uint2 wvv; short* p = (short*)&wvv;
                    #pragma unroll
                    for (int r2 = 0; r2 < 4; ++r2)
                        p[r2] = bf16b(fmaxf(acc[nt][mt][q * 4 + r2], 0.f));
                    *(uint2*)(hb + (((mw * 2 + mt) * 8 + (nw * 4 + nt)) * 2
                                    + (q >> 1)) * 1024
                                 + (q & 1) * 512 + rl * 16 + hi * 8) = wvv;
                }
        __syncthreads();                   // h ready (acc dead here)

        if (e < NEXP) {
            // ---- layer 2 (single pass over full h) + layer 3 ----
            f32x16 acc2[2];
            #pragma unroll
            for (int q = 0; q < 16; ++q) { acc2[0][q] = 0.f; acc2[1][q] = 0.f; }
            #pragma unroll
            for (int jb = 0; jb < 2; ++jb)
                #pragma unroll
                for (int k2 = 0; k2 < 8; ++k2)
                    #pragma unroll
                    for (int kh = 0; kh < 2; ++kh) {
                        s16x8 hf = *(const s16x8*)(hb + ((wave * 8 + k2) * 2 + kh) * 1024
                                                   + lane * 16);
                        s16x8 wf = *(const s16x8*)(w2c
                            + ((((size_t)e * 2 + jb) * 8 + k2) * 2 + kh) * 1024
                            + lane * 16);
                        acc2[jb] = __builtin_amdgcn_mfma_f32_32x32x16_bf16(
                            wf, hf, acc2[jb], 0, 0, 0);
                    }
            // layer 3: lane m = wave*32+rl, j = jb*32 + r2+8q+4hi
            float part = 0.f;
            #pragma unroll
            for (int jb = 0; jb < 2; ++jb)
                #pragma unroll
                for (int q = 0; q < 4; ++q) {
                    f32x4 b2v = *(const f32x4*)(b2s + e * NH2 + jb * 32 + 8 * q + 4 * hi);
                    f32x4 w3v = *(const f32x4*)(w3s + e * NH2 + jb * 32 + 8 * q + 4 * hi);
                    #pragma unroll
                    for (int r2 = 0; r2 < 4; ++r2)
                        part += fmaxf(acc2[jb][q * 4 + r2] + b2v[r2], 0.f) * w3v[r2];
                }
            part += __shfl_xor(part, 32, 64);
            if (hi == 0)
                expl[(wave * 32 + rl) * NEXP + e] = part + b3s[e];
        } else {
            // ---- gate: logits -> softmax -> combine ----
            f32x16 acc3;
            #pragma unroll
            for (int q = 0; q < 16; ++q) acc3[q] = 0.f;
            #pragma unroll
            for (int k2 = 0; k2 < 8; ++k2)
                #pragma unroll
                for (int kh = 0; kh < 2; ++kh) {
                    s16x8 hf = *(const s16x8*)(hb + ((wave * 8 + k2) * 2 + kh) * 1024
                                               + lane * 16);
                    s16x8 gf = *(const s16x8*)(wgc + (k2 * 2 + kh) * 1024 + lane * 16);
                    acc3 = __builtin_amdgcn_mfma_f32_32x32x16_bf16(
                        gf, hf, acc3, 0, 0, 0);
                }
            const int m = wave * 32 + rl;
            float lv[16], mx = -1e30f;
            #pragma unroll
            for (int q = 0; q < 4; ++q)
                #pragma unroll
                for (int r2 = 0; r2 < 4; ++r2) {
                    int j = r2 + 8 * q + 4 * hi;
                    int rg = q * 4 + r2;
                    lv[rg] = (j < NEXP) ? (acc3[rg] + bg2s[j]) : -1e30f;
                    mx = fmaxf(mx, lv[rg]);
                }
            mx = fmaxf(mx, __shfl_xor(mx, 32, 64));
            float s = 0.f, pv[16];
            #pragma unroll
            for (int rg = 0; rg < 16; ++rg) {
                pv[rg] = (lv[rg] > -1e29f) ? __expf(lv[rg] - mx) : 0.f;
                s += pv[rg];
            }
            s += __shfl_xor(s, 32, 64);
            const float inv = 1.f / s;
            #pragma unroll
            for (int q = 0; q < 4; ++q)
                #pragma unroll
                for (int r2 = 0; r2 < 4; ++r2) {
                    int j = r2 + 8 * q + 4 * hi;
                    if (j < NEXP) {
                        float g  = pv[q * 4 + r2] * inv;
                        float eo = expl[m * NEXP + j];
                        size_t o = (size_t)(row0 + m) * NEXP + j;
                        out[o] = g * eo;                        // output
                        out[(size_t)BTOT * NEXP + o] = g;       // gate_scores
                        out[(size_t)2 * BTOT * NEXP + o] = eo;  // expert_outputs
                    }
                }
        }
        __syncthreads();                   // h reads done; next expert may stage
    }
}

extern "C" void kernel_launch(void* const* d_in, const int* in_sizes, int n_in,
                              void* d_out, int out_size, void* d_ws, size_t ws_size,
                              hipStream_t stream) {
    (void)in_sizes; (void)n_in; (void)out_size; (void)ws_size;
    const float* x   = (const float*)d_in[0];
    const float* W1  = (const float*)d_in[1];
    const float* b1  = (const float*)d_in[2];
    const float* W2  = (const float*)d_in[3];
    const float* b2  = (const float*)d_in[4];
    const float* W3  = (const float*)d_in[5];
    const float* b3  = (const float*)d_in[6];
    const float* Wg1 = (const float*)d_in[7];
    const float* bg1 = (const float*)d_in[8];
    const float* Wg2 = (const float*)d_in[9];
    const float* bg2 = (const float*)d_in[10];

    // ws layout (bf16): w1t 11*25*8192 | w2t 20480*8 | wg2t 1024*8 | xt [256][25][8192]
    __bf16* w1t  = (__bf16*)d_ws;
    __bf16* w2t  = w1t + (size_t)11 * 25 * 8192;
    __bf16* wg2t = w2t + (size_t)20480 * 8;
    __bf16* xt   = wg2t + (size_t)1024 * 8;

    hipFuncSetAttribute((const void*)moe_fused,
                        hipFuncAttributeMaxDynamicSharedMemorySize, LDS_TOTAL);

    prep_w1<<<1100, 256, 0, stream>>>(W1, b1, Wg1, bg1, w1t);
    prep_w2<<<80, 256, 0, stream>>>(W2, w2t);
    prep_wg2<<<4, 256, 0, stream>>>(Wg2, wg2t);
    moe_fused<<<BTOT / BM, 512, LDS_TOTAL, stream>>>(
        x, xt, b2, W3, b3, bg2, w1t, w2t, wg2t, (float*)d_out);
}

// Round 19
// 329.622 us; speedup vs baseline: 1.0569x; 1.0569x over previous
//
#include <hip/hip_runtime.h>
#include <hip/hip_bf16.h>
#include <stdint.h>

// ---------------- problem dims ----------------
#define BTOT   65536
#define DIN    784
#define NH1    256
#define NH2    64
#define NEXP   10
#define BM     256
#define NKS1   25      // K1 = 800 (784 + bias row @784 + zeros), 25 steps of 32

// ---------------- LDS layout (bytes) ----------------
// 4-slot staging ring, 32 KB each (x 16K | w 16K). h (128 KB, FULL) overlays
// the whole ring — used only after the K-loop fully drains.
#define SLOT(s)   (lds + (s) * 32768)
#define EXPL_OFF  131072                   // [256 m][10 e] f32 = 10240
#define B2S_OFF   141312                   // [10][64] f32 = 2560
#define W3S_OFF   143872                   // [10][64] f32 = 2560
#define B3S_OFF   146432                   // 64
#define BG2S_OFF  146496                   // 64
#define LDS_TOTAL 146560

typedef short s16x8  __attribute__((ext_vector_type(8)));
typedef float f32x4  __attribute__((ext_vector_type(4)));
typedef float f32x16 __attribute__((ext_vector_type(16)));

__device__ __forceinline__ short bf16b(float v) {
    __bf16 b = (__bf16)v;
    return __builtin_bit_cast(short, b);
}

__device__ __forceinline__ void g2l16(const void* g, void* l) {
    __builtin_amdgcn_global_load_lds(
        (const __attribute__((address_space(1))) unsigned char*)g,
        (__attribute__((address_space(3))) unsigned char*)l, 16, 0, 0);
}

// ---------------- prep: fragment-order weights (bf16, b1 folded) ------------
// w1t [e11][ks25][nb8][kh2][lane64][8]: n=nb*32+(lane&31),
// k=ks*32+kh*16+(lane>>5)*8+j; k==784 -> bias; e==10 -> gate Wg1/bg1.
__global__ void prep_w1(const float* __restrict__ W1, const float* __restrict__ b1,
                        const float* __restrict__ Wg1, const float* __restrict__ bg1,
                        __bf16* __restrict__ dst) {
    int t = blockIdx.x * 256 + threadIdx.x;          // < 281600
    int lane = t & 63;
    int kh = (t >> 6) & 1;
    int nb = (t >> 7) & 7;
    int r  = t >> 10;
    int ks = r % 25, e = r / 25;
    int n  = nb * 32 + (lane & 31);
    int k0 = ks * 32 + kh * 16 + (lane >> 5) * 8;
    const float* src  = (e < NEXP) ? (W1 + (size_t)e * DIN * NH1) : Wg1;
    const float* bias = (e < NEXP) ? (b1 + e * NH1) : bg1;
    s16x8 o;
    #pragma unroll
    for (int j = 0; j < 8; ++j) {
        int k = k0 + j;
        float v = (k < DIN) ? src[(size_t)k * NH1 + n]
                            : ((k == DIN) ? bias[n] : 0.f);
        o[j] = bf16b(v);
    }
    *(s16x8*)((short*)dst + (size_t)t * 8) = o;
}

// w2t [e10][jb2][ks8][kh2][lane64][8]: n=jb*32+(lane&31), K2=256.
__global__ void prep_w2(const float* __restrict__ W2, __bf16* __restrict__ dst) {
    int t = blockIdx.x * 256 + threadIdx.x;          // < 20480
    int lane = t & 63;
    int kh = (t >> 6) & 1;
    int ks = (t >> 7) & 7;
    int jb = (t >> 10) & 1;
    int e  = t >> 11;
    int n  = jb * 32 + (lane & 31);
    int k0 = ks * 32 + kh * 16 + (lane >> 5) * 8;
    s16x8 o;
    #pragma unroll
    for (int j = 0; j < 8; ++j)
        o[j] = bf16b(W2[((size_t)e * NH1 + k0 + j) * NH2 + n]);
    *(s16x8*)((short*)dst + (size_t)t * 8) = o;
}

// wg2t [ks8][kh2][lane64][8]: col = lane&31 (valid <10), K2=256.
__global__ void prep_wg2(const float* __restrict__ Wg2, __bf16* __restrict__ dst) {
    int t = blockIdx.x * 256 + threadIdx.x;
    if (t >= 1024) return;
    int lane = t & 63;
    int kh = (t >> 6) & 1;
    int ks = t >> 7;
    int n  = lane & 31;
    int k0 = ks * 32 + kh * 16 + (lane >> 5) * 8;
    s16x8 o;
    #pragma unroll
    for (int j = 0; j < 8; ++j)
        o[j] = bf16b((n < NEXP) ? Wg2[(size_t)(k0 + j) * NEXP + n] : 0.f);
    *(s16x8*)((short*)dst + (size_t)t * 8) = o;
}

// ---- staging + body macros ----
#define STAGE(S, E, KS) {                                                     \
        const char* xs_ = xtc + ((size_t)(KS) << 14) + tid * 16;              \
        char* xd_ = SLOT(S) + tid * 16;                                       \
        g2l16(xs_, xd_); g2l16(xs_ + 8192, xd_ + 8192);                       \
        const char* ws_ = w1c + (((size_t)(E) * 25 + (KS)) << 14) + tid * 16; \
        char* wd_ = SLOT(S) + 16384 + tid * 16;                               \
        g2l16(ws_, wd_); g2l16(ws_ + 8192, wd_ + 8192); }

// w-only stage (e=0 path)
#define WSTAGE1(S, KS) {                                                      \
        const char* ws_ = w1c + ((size_t)(KS) << 14) + tid * 16;              \
        char* wd_ = SLOT(S) + 16384 + tid * 16;                               \
        g2l16(ws_, wd_); g2l16(ws_ + 8192, wd_ + 8192); }

// e=0: load 16 fp32 of x (row xrow, k-half xkh) into xf; ks=24 upper half is
// the bias-1 + zero pad (k=784..799).
#define XLOAD(KS) { if ((KS) < 24 || xkh == 0) {                              \
            _Pragma("unroll") for (int i4 = 0; i4 < 4; ++i4)                  \
                *(float4*)(xf + 4 * i4) =                                     \
                    *(const float4*)(xrp + (KS) * 32 + 4 * i4);               \
        } else { _Pragma("unroll") for (int i4 = 0; i4 < 16; ++i4)            \
                     xf[i4] = 0.f;                                            \
                 xf[0] = 1.f; } }

// e=0: convert + write to LDS slot x-region AND write-through fragment-order
// xt (global; only this block reads it back).
#define XWRITE(B, KS) { s16x8 l8, h8;                                         \
        _Pragma("unroll") for (int j = 0; j < 8; ++j) {                       \
            l8[j] = bf16b(xf[j]); h8[j] = bf16b(xf[8 + j]); }                 \
        *(s16x8*)(SLOT(B) + xoff)       = l8;                                 \
        *(s16x8*)(SLOT(B) + xoff + 512) = h8;                                 \
        char* xg_ = xtw + ((size_t)(KS) << 14) + xoff;                        \
        *(s16x8*)xg_ = l8; *(s16x8*)(xg_ + 512) = h8; }

#define COMPUTE(S) {                                                          \
        const char* ab = SLOT(S) + mw * 4096 + lane * 16;                     \
        const char* wb = SLOT(S) + 16384 + nw * 8192 + lane * 16;             \
        s16x8 xv[2][2], wv[4][2];                                             \
        _Pragma("unroll") for (int mt = 0; mt < 2; ++mt)                      \
            _Pragma("unroll") for (int kh = 0; kh < 2; ++kh)                  \
                xv[mt][kh] = *(const s16x8*)(ab + (mt * 2 + kh) * 1024);      \
        _Pragma("unroll") for (int nt = 0; nt < 4; ++nt)                      \
            _Pragma("unroll") for (int kh = 0; kh < 2; ++kh)                  \
                wv[nt][kh] = *(const s16x8*)(wb + (nt * 2 + kh) * 1024);      \
        _Pragma("unroll") for (int kh = 0; kh < 2; ++kh)                      \
            _Pragma("unroll") for (int nt = 0; nt < 4; ++nt)                  \
                _Pragma("unroll") for (int mt = 0; mt < 2; ++mt)              \
                    acc[nt][mt] = __builtin_amdgcn_mfma_f32_32x32x16_bf16(    \
                        wv[nt][kh], xv[mt][kh], acc[nt][mt], 0, 0, 0); }

// counted-vmcnt sync wall (wait-own-ops THEN barrier)
#define RING_SYNC(VN) {                                                       \
        asm volatile("s_waitcnt vmcnt(" #VN ")" ::: "memory");                \
        __builtin_amdgcn_s_barrier();                                         \
        asm volatile("" ::: "memory"); }

// ring body (r16 proven form): sync -> compute -> stage ks+3 (WAR-safe)
#define BODY(S, KS) {                                                         \
        RING_SYNC(8)                                                          \
        COMPUTE(S)                                                            \
        STAGE(((S) + 3) & 3, e, (KS) + 3) }

// e=0 counted sync: drain loads+g2l (oldest), keep 2 xt stores in flight;
// lgkmcnt(0) makes ds_writes barrier-visible.
#define E0SYNC() {                                                            \
        asm volatile("s_waitcnt vmcnt(2) lgkmcnt(0)" ::: "memory");           \
        __builtin_amdgcn_s_barrier();                                         \
        asm volatile("" ::: "memory"); }

// e=0 body (ks<24): sync -> issue x-loads + W-g2l EARLY -> MFMA (hides load
// latency) -> convert+write (loads done by now). Pins keep the order.
#define E0BODY(CUR, KS) {                                                     \
        E0SYNC()                                                              \
        XLOAD((KS) + 1)                                                       \
        WSTAGE1((CUR) ^ 1, (KS) + 1)                                          \
        __builtin_amdgcn_sched_barrier(0);                                    \
        COMPUTE(CUR)                                                          \
        __builtin_amdgcn_sched_barrier(0);                                    \
        XWRITE((CUR) ^ 1, (KS) + 1) }

// ---------------- fused MoE kernel ----------------
// 256 blocks x 512 thr (8 waves, 1 block/CU, 2 waves/SIMD). Per expert:
// 256x256 layer-1 GEMM, K-step 32. e=0: counted 2-slot loop converting x
// fp32->bf16 into the slot AND writing fragment-order xt (stores never
// drained in-loop). e>=1 + gate: r16's 4-slot depth-3 counted ring. h
// written FULL (ring overlay) -> no acc/acc2 lifetime overlap.
// mfma(W, x): D[n][m], m = lane&31, n = (r&3)+8*(r>>2)+4*(lane>>5).
__global__ void __launch_bounds__(512)
__attribute__((amdgpu_waves_per_eu(2, 2)))
moe_fused(const float* __restrict__ x, __bf16* __restrict__ xt,
          const float* __restrict__ b2g, const float* __restrict__ W3,
          const float* __restrict__ b3, const float* __restrict__ bg2,
          const __bf16* __restrict__ w1t, const __bf16* __restrict__ w2t,
          const __bf16* __restrict__ wg2t, float* __restrict__ out)
{
    extern __shared__ char lds[];
    char*  hb   = lds;                     // FULL h: [mtile8][ks2_8][kh2][1024B]
    float* expl = (float*)(lds + EXPL_OFF);
    float* b2s  = (float*)(lds + B2S_OFF);
    float* w3s  = (float*)(lds + W3S_OFF);
    float* b3s  = (float*)(lds + B3S_OFF);
    float* bg2s = (float*)(lds + BG2S_OFF);

    const int tid  = threadIdx.x;
    const int lane = tid & 63;
    const int wave = tid >> 6;             // 0..7
    const int rl   = lane & 31;
    const int hi   = lane >> 5;
    const int mw   = wave >> 1;            // 0..3 (64-row slice)
    const int nw   = wave & 1;             // 0..1 (128-col half)
    const int row0 = blockIdx.x * BM;
    const char* w1c = (const char*)w1t;
    const char* w2c = (const char*)w2t;
    const char* wgc = (const char*)wg2t;
    const char* xtc = (const char*)xt + ((size_t)blockIdx.x * 25 << 14);
    char*       xtw = (char*)xt + ((size_t)blockIdx.x * 25 << 14);

    // e=0 x-staging coords: thread -> (row, k-half)
    const int xrow = tid >> 1, xkh = tid & 1;
    const float* xrp = x + (size_t)(row0 + xrow) * DIN + xkh * 16;
    const int xoff = ((xrow >> 5) * 2 + xkh) * 1024 + (xrow & 31) * 16;
    float xf[16];

    for (int i = tid; i < NEXP * NH2; i += 512) { b2s[i] = b2g[i]; w3s[i] = W3[i]; }
    if (tid < NEXP) { b3s[tid] = b3[tid]; bg2s[tid] = bg2[tid]; }
    __syncthreads();                       // drains vmcnt -> known 0

    f32x16 acc[4][2];                      // [nt][mt] (layer-1)

    #pragma unroll 1
    for (int e = 0; e <= NEXP; ++e) {
        #pragma unroll
        for (int nt = 0; nt < 4; ++nt)
            #pragma unroll
            for (int mt = 0; mt < 2; ++mt)
                #pragma unroll
                for (int q = 0; q < 16; ++q) acc[nt][mt][q] = 0.f;

        if (e == 0) {
            // ---- e=0: counted 2-slot loop, x fp32->bf16 + xt write-through ----
            XLOAD(0)
            WSTAGE1(0, 0)
            XWRITE(0, 0)                   // dep-wait retires loads before stores
            #pragma unroll 1
            for (int T = 0; T < 12; ++T) {
                E0BODY(0, 2 * T)
                E0BODY(1, 2 * T + 1)
            }
            // peeled ks=24 (slot 0; staged during body ks=23)
            E0SYNC()
            COMPUTE(0)
            __syncthreads();               // drains xt stores; h may overlay
        } else {
            // ---- e>=1 / gate: 4-slot depth-3 counted ring (r16 form) ----
            STAGE(0, e, 0)
            STAGE(1, e, 1)
            STAGE(2, e, 2)
            #pragma unroll 1
            for (int T = 0; T < 5; ++T) {
                const int k4 = 4 * T;
                BODY(0, k4)
                BODY(1, k4 + 1)
                BODY(2, k4 + 2)
                BODY(3, k4 + 3)
            }
            BODY(0, 20)                    // stages ks=23 -> slot 3
            BODY(1, 21)                    // stages ks=24 -> slot 0
            RING_SYNC(8)  COMPUTE(2)       // ks=22 (no stage)
            RING_SYNC(4)  COMPUTE(3)       // ks=23
            RING_SYNC(0)  COMPUTE(0)       // ks=24
            __syncthreads();               // all ring reads done; h may overlay
        }

        // ---- h-write (FULL): value (nt,mt,q,r2) ->
        //      h[m=(mw*2+mt)*32+rl][n=nw*128+nt*32+(r2+8q+4hi)]
        #pragma unroll
        for (int mt = 0; mt < 2; ++mt)
            #pragma unroll
            for (int nt = 0; nt < 4; ++nt)
                #pragma unroll
                for (int q = 0; q < 4; ++q) {
                    uint2 wvv; short* p = (short*)&wvv;
                    #pragma unroll
                    for (int r2 = 0; r2 < 4; ++r2)
                        p[r2] = bf16b(fmaxf(acc[nt][mt][q * 4 + r2], 0.f));
                    *(uint2*)(hb + (((mw * 2 + mt) * 8 + (nw * 4 + nt)) * 2
                                    + (q >> 1)) * 1024
                                 + (q & 1) * 512 + rl * 16 + hi * 8) = wvv;
                }
        __syncthreads();                   // h ready (acc dead here)

        if (e < NEXP) {
            // ---- layer 2 (single pass over full h) + layer 3 ----
            f32x16 acc2[2];
            #pragma unroll
            for (int q = 0; q < 16; ++q) { acc2[0][q] = 0.f; acc2[1][q] = 0.f; }
            #pragma unroll
            for (int jb = 0; jb < 2; ++jb)
                #pragma unroll
                for (int k2 = 0; k2 < 8; ++k2)
                    #pragma unroll
                    for (int kh = 0; kh < 2; ++kh) {
                        s16x8 hf = *(const s16x8*)(hb + ((wave * 8 + k2) * 2 + kh) * 1024
                                                   + lane * 16);
                        s16x8 wf = *(const s16x8*)(w2c
                            + ((((size_t)e * 2 + jb) * 8 + k2) * 2 + kh) * 1024
                            + lane * 16);
                        acc2[jb] = __builtin_amdgcn_mfma_f32_32x32x16_bf16(
                            wf, hf, acc2[jb], 0, 0, 0);
                    }
            // layer 3: lane m = wave*32+rl, j = jb*32 + r2+8q+4hi
            float part = 0.f;
            #pragma unroll
            for (int jb = 0; jb < 2; ++jb)
                #pragma unroll
                for (int q = 0; q < 4; ++q) {
                    f32x4 b2v = *(const f32x4*)(b2s + e * NH2 + jb * 32 + 8 * q + 4 * hi);
                    f32x4 w3v = *(const f32x4*)(w3s + e * NH2 + jb * 32 + 8 * q + 4 * hi);
                    #pragma unroll
                    for (int r2 = 0; r2 < 4; ++r2)
                        part += fmaxf(acc2[jb][q * 4 + r2] + b2v[r2], 0.f) * w3v[r2];
                }
            part += __shfl_xor(part, 32, 64);
            if (hi == 0)
                expl[(wave * 32 + rl) * NEXP + e] = part + b3s[e];
        } else {
            // ---- gate: logits -> softmax -> combine ----
            f32x16 acc3;
            #pragma unroll
            for (int q = 0; q < 16; ++q) acc3[q] = 0.f;
            #pragma unroll
            for (int k2 = 0; k2 < 8; ++k2)
                #pragma unroll
                for (int kh = 0; kh < 2; ++kh) {
                    s16x8 hf = *(const s16x8*)(hb + ((wave * 8 + k2) * 2 + kh) * 1024
                                               + lane * 16);
                    s16x8 gf = *(const s16x8*)(wgc + (k2 * 2 + kh) * 1024 + lane * 16);
                    acc3 = __builtin_amdgcn_mfma_f32_32x32x16_bf16(
                        gf, hf, acc3, 0, 0, 0);
                }
            const int m = wave * 32 + rl;
            float lv[16], mx = -1e30f;
            #pragma unroll
            for (int q = 0; q < 4; ++q)
                #pragma unroll
                for (int r2 = 0; r2 < 4; ++r2) {
                    int j = r2 + 8 * q + 4 * hi;
                    int rg = q * 4 + r2;
                    lv[rg] = (j < NEXP) ? (acc3[rg] + bg2s[j]) : -1e30f;
                    mx = fmaxf(mx, lv[rg]);
                }
            mx = fmaxf(mx, __shfl_xor(mx, 32, 64));
            float s = 0.f, pv[16];
            #pragma unroll
            for (int rg = 0; rg < 16; ++rg) {
                pv[rg] = (lv[rg] > -1e29f) ? __expf(lv[rg] - mx) : 0.f;
                s += pv[rg];
            }
            s += __shfl_xor(s, 32, 64);
            const float inv = 1.f / s;
            #pragma unroll
            for (int q = 0; q < 4; ++q)
                #pragma unroll
                for (int r2 = 0; r2 < 4; ++r2) {
                    int j = r2 + 8 * q + 4 * hi;
                    if (j < NEXP) {
                        float g  = pv[q * 4 + r2] * inv;
                        float eo = expl[m * NEXP + j];
                        size_t o = (size_t)(row0 + m) * NEXP + j;
                        out[o] = g * eo;                        // output
                        out[(size_t)BTOT * NEXP + o] = g;       // gate_scores
                        out[(size_t)2 * BTOT * NEXP + o] = eo;  // expert_outputs
                    }
                }
        }
        __syncthreads();                   // h reads done; next expert may stage
    }
}

extern "C" void kernel_launch(void* const* d_in, const int* in_sizes, int n_in,
                              void* d_out, int out_size, void* d_ws, size_t ws_size,
                              hipStream_t stream) {
    (void)in_sizes; (void)n_in; (void)out_size; (void)ws_size;
    const float* x   = (const float*)d_in[0];
    const float* W1  = (const float*)d_in[1];
    const float* b1  = (const float*)d_in[2];
    const float* W2  = (const float*)d_in[3];
    const float* b2  = (const float*)d_in[4];
    const float* W3  = (const float*)d_in[5];
    const float* b3  = (const float*)d_in[6];
    const float* Wg1 = (const float*)d_in[7];
    const float* bg1 = (const float*)d_in[8];
    const float* Wg2 = (const float*)d_in[9];
    const float* bg2 = (const float*)d_in[10];

    // ws layout (bf16): w1t 11*25*8192 | w2t 20480*8 | wg2t 1024*8 | xt [256][25][8192]
    __bf16* w1t  = (__bf16*)d_ws;
    __bf16* w2t  = w1t + (size_t)11 * 25 * 8192;
    __bf16* wg2t = w2t + (size_t)20480 * 8;
    __bf16* xt   = wg2t + (size_t)1024 * 8;

    hipFuncSetAttribute((const void*)moe_fused,
                        hipFuncAttributeMaxDynamicSharedMemorySize, LDS_TOTAL);

    prep_w1<<<1100, 256, 0, stream>>>(W1, b1, Wg1, bg1, w1t);
    prep_w2<<<80, 256, 0, stream>>>(W2, w2t);
    prep_wg2<<<4, 256, 0, stream>>>(Wg2, wg2t);
    moe_fused<<<BTOT / BM, 512, LDS_TOTAL, stream>>>(
        x, xt, b2, W3, b3, bg2, w1t, w2t, wg2t, (float*)d_out);
}